// Round 1
// baseline (60.859 us; speedup 1.0000x reference)
//
#include <hip/hip_runtime.h>

// Problem shape (fixed by reference setup_inputs):
//   x: [B=32, C=256, H=64, W=64] fp32, conv_w: [1,1,3] fp32
//   out: [B, 3, H, W] fp32
#define B  32
#define C  256
#define HW 4096          // 64*64
#define BC (B * C)       // 8192

// ---------------------------------------------------------------------------
// Kernel 1: per-(b,c) spatial mean.  One block per (b,c) slice (16 KB).
// 256 threads x 4 float4 each = 4096 floats.  Wave shuffle + LDS reduce.
// ---------------------------------------------------------------------------
__global__ __launch_bounds__(256) void eca_mean_kernel(
    const float* __restrict__ x, float* __restrict__ means) {
    const int bc  = blockIdx.x;
    const int tid = threadIdx.x;
    const float4* p4 = reinterpret_cast<const float4*>(x + (size_t)bc * HW);

    float sum = 0.f;
#pragma unroll
    for (int i = 0; i < 4; ++i) {
        float4 v = p4[tid + i * 256];
        sum += (v.x + v.y) + (v.z + v.w);
    }
    // 64-lane wave reduce
#pragma unroll
    for (int off = 32; off > 0; off >>= 1)
        sum += __shfl_down(sum, off);

    __shared__ float s[4];
    const int wave = tid >> 6;
    if ((tid & 63) == 0) s[wave] = sum;
    __syncthreads();
    if (tid == 0) {
        float t = (s[0] + s[1]) + (s[2] + s[3]);
        means[bc] = t * (1.0f / HW);
    }
}

// ---------------------------------------------------------------------------
// Kernel 2: conv1d(k=3, SAME, cross-correlation) over channel axis + top-3.
// One block per batch (32 blocks, 256 threads = one per channel).
// Sigmoid is monotonic -> top-k of sigmoid(y) == top-k of y (skip sigmoid).
// lax.top_k tie-break: smaller index wins -> strict '>' serial scan matches.
// ---------------------------------------------------------------------------
__global__ __launch_bounds__(256) void eca_conv_topk_kernel(
    const float* __restrict__ means, const float* __restrict__ w,
    int* __restrict__ idx) {
    const int b = blockIdx.x;
    const int c = threadIdx.x;
    const float* m = means + b * C;

    const float w0 = w[0], w1 = w[1], w2 = w[2];
    const float ym1 = (c > 0)     ? m[c - 1] : 0.f;  // SAME zero-pad
    const float y0  = m[c];
    const float yp1 = (c < C - 1) ? m[c + 1] : 0.f;
    const float y = w0 * ym1 + w1 * y0 + w2 * yp1;

    __shared__ float svals[C];
    svals[c] = y;
    __syncthreads();

    if (c == 0) {
        int   i0 = -1, i1 = -1, i2 = -1;
        float v0 = -INFINITY, v1 = -INFINITY, v2 = -INFINITY;
        for (int i = 0; i < C; ++i) {
            const float v = svals[i];
            if (v > v0)      { v2 = v1; i2 = i1; v1 = v0; i1 = i0; v0 = v; i0 = i; }
            else if (v > v1) { v2 = v1; i2 = i1; v1 = v;  i1 = i; }
            else if (v > v2) { v2 = v;  i2 = i; }
        }
        idx[b * 3 + 0] = i0;
        idx[b * 3 + 1] = i1;
        idx[b * 3 + 2] = i2;
    }
}

// ---------------------------------------------------------------------------
// Kernel 3: gather top-3 channels per batch into out [B,3,H,W].
// float4-vectorized copy; 98304 float4s total.
// ---------------------------------------------------------------------------
__global__ __launch_bounds__(256) void eca_gather_kernel(
    const float* __restrict__ x, const int* __restrict__ idx,
    float* __restrict__ out) {
    const int t   = blockIdx.x * blockDim.x + threadIdx.x;  // 0 .. 98303
    const int hw4 = t & (HW / 4 - 1);   // 1024 float4 per (b,j) slice
    const int bj  = t >> 10;            // 0 .. 95
    const int b   = bj / 3;
    const int ch  = idx[bj];

    const float4* src = reinterpret_cast<const float4*>(
        x + ((size_t)(b * C + ch)) * HW);
    float4* dst = reinterpret_cast<float4*>(out + (size_t)bj * HW);
    dst[hw4] = src[hw4];
}

extern "C" void kernel_launch(void* const* d_in, const int* in_sizes, int n_in,
                              void* d_out, int out_size, void* d_ws, size_t ws_size,
                              hipStream_t stream) {
    const float* x      = (const float*)d_in[0];
    const float* conv_w = (const float*)d_in[1];
    float* out = (float*)d_out;

    // Workspace layout: [0, 32KB) means (8192 f32), [32KB, ...) idx (96 i32)
    float* means = (float*)d_ws;
    int*   idx   = (int*)((char*)d_ws + BC * sizeof(float));

    eca_mean_kernel<<<BC, 256, 0, stream>>>(x, means);
    eca_conv_topk_kernel<<<B, 256, 0, stream>>>(means, conv_w, idx);
    eca_gather_kernel<<<(B * 3 * HW / 4) / 256, 256, 0, stream>>>(x, idx, out);
}

// Round 2
// 28.845 us; speedup vs baseline: 2.1098x; 2.1098x over previous
//
#include <hip/hip_runtime.h>

// Problem shape (fixed by reference setup_inputs):
//   x: [B=32, C=256, H=64, W=64] fp32, conv_w: [1,1,3] fp32
//   out: [B, 3, H, W] fp32
#define B  32
#define C  256
#define HW 4096          // 64*64
#define BC (B * C)       // 8192

// ---------------------------------------------------------------------------
// Kernel 1: per-(b,c) spatial mean. ONE WAVE per slice: 64 lanes x 16 float4
// = 4096 floats. 16 independent loads in flight per lane (256 B/lane MLP),
// pure shuffle reduce, no LDS, no __syncthreads.
// 2048 blocks x 256 threads = 8192 waves = 8192 slices.
// ---------------------------------------------------------------------------
__global__ __launch_bounds__(256) void eca_mean_kernel(
    const float* __restrict__ x, float* __restrict__ means) {
    const int wid  = (blockIdx.x * 256 + threadIdx.x) >> 6;  // slice id
    const int lane = threadIdx.x & 63;
    const float4* p4 = reinterpret_cast<const float4*>(x + (size_t)wid * HW);

    float sum = 0.f;
#pragma unroll
    for (int i = 0; i < 16; ++i) {
        float4 v = p4[lane + i * 64];
        sum += (v.x + v.y) + (v.z + v.w);
    }
#pragma unroll
    for (int off = 32; off > 0; off >>= 1)
        sum += __shfl_down(sum, off);

    if (lane == 0) means[wid] = sum * (1.0f / HW);
}

// ---------------------------------------------------------------------------
// Kernel 2: fused conv1d(k=3,SAME) + top-3 + gather.
// Grid: 32 batches x 12 chunks = 384 blocks, 256 threads (one per channel).
// Each block redundantly computes conv (1 KB of L2-hit means) and a
// wave-parallel top-3, then copies its 4 KB chunk of the output.
//
// Top-3 semantics: sigmoid is monotonic -> skip it. lax.top_k tie-break is
// smaller index -> key = (monotonic_u32(y) << 8) | (255 - c); max over keys
// picks larger value, then smaller channel on ties.
// ---------------------------------------------------------------------------
__global__ __launch_bounds__(256) void eca_fused_kernel(
    const float* __restrict__ x, const float* __restrict__ means,
    const float* __restrict__ w, float* __restrict__ out) {
    const int b  = blockIdx.x / 12;
    const int j  = blockIdx.x % 12;
    const int jj = j >> 2;   // which of the 3 output slices
    const int q  = j & 3;    // which quarter of the slice
    const int c  = threadIdx.x;

    const float* m = means + b * C;
    const float ym1 = (c > 0)     ? m[c - 1] : 0.f;  // SAME zero-pad
    const float y0  = m[c];
    const float yp1 = (c < C - 1) ? m[c + 1] : 0.f;
    const float y = w[0] * ym1 + w[1] * y0 + w[2] * yp1;

    // Monotonic float->uint mapping (total order matching float compare)
    unsigned int u = __float_as_uint(y);
    u = (u & 0x80000000u) ? ~u : (u | 0x80000000u);
    unsigned long long key =
        ((unsigned long long)u << 8) | (unsigned long long)(255 - c);

    __shared__ unsigned long long swave[4];
    __shared__ unsigned long long swin;

    int mych = -1;          // the channel this block will copy (r == jj winner)
    bool excluded = false;

#pragma unroll
    for (int r = 0; r < 3; ++r) {
        unsigned long long k = excluded ? 0ULL : key;
#pragma unroll
        for (int off = 32; off > 0; off >>= 1) {
            unsigned long long o = __shfl_down(k, off);
            k = (o > k) ? o : k;
        }
        if ((threadIdx.x & 63) == 0) swave[threadIdx.x >> 6] = k;
        __syncthreads();
        if (threadIdx.x == 0) {
            unsigned long long a0 = swave[0], a1 = swave[1];
            unsigned long long a2 = swave[2], a3 = swave[3];
            unsigned long long mx = (a0 > a1) ? a0 : a1;
            unsigned long long my = (a2 > a3) ? a2 : a3;
            swin = (mx > my) ? mx : my;
        }
        __syncthreads();
        const int wc = 255 - (int)(swin & 0xFFULL);
        if (r == jj)  mych = wc;
        if (wc == c)  excluded = true;
        // next round's swave write is after the sync above; swin rewrite is
        // separated from this read by the next round's first __syncthreads()
    }

    // Copy quarter q of slice (b, mych) -> out slice (b, jj).
    const float4* src = reinterpret_cast<const float4*>(
        x + ((size_t)(b * C + mych)) * HW);
    float4* dst = reinterpret_cast<float4*>(
        out + ((size_t)(b * 3 + jj)) * HW);
    const int o = q * 256 + c;   // 1024 float4 per slice, 256 per quarter
    dst[o] = src[o];
}

extern "C" void kernel_launch(void* const* d_in, const int* in_sizes, int n_in,
                              void* d_out, int out_size, void* d_ws, size_t ws_size,
                              hipStream_t stream) {
    const float* x      = (const float*)d_in[0];
    const float* conv_w = (const float*)d_in[1];
    float* out = (float*)d_out;

    float* means = (float*)d_ws;   // 8192 f32 = 32 KB

    eca_mean_kernel<<<BC / 4, 256, 0, stream>>>(x, means);
    eca_fused_kernel<<<B * 12, 256, 0, stream>>>(x, means, conv_w, out);
}